// Round 1
// baseline (27982.861 us; speedup 1.0000x reference)
//
#include <hip/hip_runtime.h>

// ---------------------------------------------------------------------------
// RNN_MultiRegional_D1D2: 1000-step Euler RNN, state TOT=1676, batch 32.
// Round 0 design:
//   - build_kernel: constructs block-compacted W (per-region rows, layout
//     Wc[k][il] so lanes load coalesced float4 over output index) + copies
//     hn/xn into ws state. Runs every call (ws is re-poisoned by harness).
//   - step_kernel x1000: grid = 32 batches x 7 region slots. Each block:
//     load h[b] to LDS, 4 waves split K, float4 W loads, LDS reduce,
//     Euler update + relu, write h to the *other* h buffer (double-buffered
//     to avoid cross-block RAW race within a step).
// ws layout (floats): [Wc 774656][hA 53632][hB 53632][x 53632] = 3.74 MB
// ---------------------------------------------------------------------------

#define HIDN  256
#define INPN  64
#define FSIN  76
#define TOT   1676
#define BATCH 32
#define NSTEP 1000
#define DT    0.01f
#define SCALE 1.41421356237e-3f   // sqrt(2*0.01)*0.01

#define WTOTAL 774656
#define HA_OFF 774656
#define HB_OFF 828288
#define X_OFF  881920

// slots: 0 str, 1 gpe, 2 stn, 3 snr, 4 thal, 5 alm, 6 fsi(+iti epilogue)
__device__ const int g_segstart[7][5] = {
  {0, 1024, 1280, 1536, 1600},
  {128, 0, 0, 0, 0},
  {256, 0, 0, 0, 0},
  {0, 512, 0, 0, 0},
  {768, 1280, 0, 0, 0},
  {1024, 1280, 0, 0, 0},
  {1024, 1280, 1536, 1600, 0}};
__device__ const int g_seglen[7][5] = {
  {256, 256, 256, 64, 76},
  {128, 0, 0, 0, 0},
  {256, 0, 0, 0, 0},
  {128, 256, 0, 0, 0},
  {256, 256, 0, 0, 0},
  {256, 256, 0, 0, 0},
  {256, 256, 64, 76, 0}};
__device__ const int g_nseg[7]  = {5, 1, 1, 2, 2, 2, 4};
__device__ const int g_K[7]     = {908, 128, 256, 384, 512, 512, 652};
__device__ const int g_ip[7]    = {256, 256, 256, 256, 256, 256, 128};
__device__ const int g_ibase[7] = {0, 256, 512, 768, 1024, 1280, 1600};
__device__ const int g_woff[7]  = {0, 232448, 265216, 330752, 429056, 560128, 691200};
__device__ const float g_tonic[7] = {0.f, 1.f, 1.f, 0.f, 1.f, 0.f, 0.f};

__global__ __launch_bounds__(256)
void build_kernel(const float* __restrict__ sparse,   const float* __restrict__ str2str,
                  const float* __restrict__ thal2alm, const float* __restrict__ thal2str,
                  const float* __restrict__ alm2alm,  const float* __restrict__ alm2str,
                  const float* __restrict__ alm2thal, const float* __restrict__ str2snr,
                  const float* __restrict__ str2gpe,  const float* __restrict__ gpe2stn,
                  const float* __restrict__ stn2snr,  const float* __restrict__ snr2thal,
                  const float* __restrict__ fsi2str,  const float* __restrict__ thal2fsi,
                  const float* __restrict__ alm2fsi,  const float* __restrict__ iti2fsi,
                  const float* __restrict__ fsi2fsi,  const float* __restrict__ inp_str,
                  const float* __restrict__ hn,       const float* __restrict__ xn,
                  float* __restrict__ ws)
{
  int idx = blockIdx.x * 256 + threadIdx.x;
  if (idx < WTOTAL) {
    int r = 0;
    for (int rr = 6; rr >= 0; --rr) { if (idx >= g_woff[rr]) { r = rr; break; } }
    int rel = idx - g_woff[r];
    int ip = g_ip[r];
    int k  = (ip == 256) ? (rel >> 8) : (rel >> 7);
    int il = rel & (ip - 1);
    // map k -> global source column j
    int j = 0, kk = k;
    for (int s = 0; s < g_nseg[r]; ++s) {
      int len = g_seglen[r][s];
      if (kk < len) { j = g_segstart[r][s] + kk; break; }
      kk -= len;
    }
    float v = 0.f;
    if (!(r == 6 && il >= FSIN)) {
      switch (r) {
      case 0: { // str rows
        if (j < 256) {
          int lj = j;
          bool same = ((il < 128) == (lj < 128));
          float w = fmaxf(str2str[il * HIDN + lj], 0.f);
          v = same ? -(sparse[il * HIDN + lj] * w) : 0.f;
        } else if (j < 1280) {
          v = fmaxf(thal2str[il * HIDN + (j - 1024)], 0.f);
        } else if (j < 1536) {
          int lj = j - 1280;
          v = (lj < 180) ? fmaxf(alm2str[il * HIDN + lj], 0.f) : 0.f;
        } else if (j < 1600) {
          v = fmaxf(inp_str[il * INPN + (j - 1536)], 0.f);
        } else {
          v = -fmaxf(fsi2str[il * FSIN + (j - 1600)], 0.f);
        }
      } break;
      case 1: // gpe rows: str D2 half (j in [128,256))
        v = -fmaxf(str2gpe[il * HIDN + j], 0.f);
        break;
      case 2: // stn rows: gpe
        v = -fmaxf(gpe2stn[il * HIDN + (j - 256)], 0.f);
        break;
      case 3: // snr rows: str D1 half, stn
        v = (j < 128) ? -fmaxf(str2snr[il * HIDN + j], 0.f)
                      :  fmaxf(stn2snr[il * HIDN + (j - 512)], 0.f);
        break;
      case 4: // thal rows: snr, alm(masked)
        if (j < 1024) v = -fmaxf(snr2thal[il * HIDN + (j - 768)], 0.f);
        else { int lj = j - 1280; v = (lj < 180) ? fmaxf(alm2thal[il * HIDN + lj], 0.f) : 0.f; }
        break;
      case 5: // alm rows: thal, alm (Dale diag on cols)
        if (j < 1280) v = fmaxf(thal2alm[il * HIDN + (j - 1024)], 0.f);
        else { int lj = j - 1280; float w = fmaxf(alm2alm[il * HIDN + lj], 0.f); v = (lj >= 180) ? -w : w; }
        break;
      default: // 6: fsi rows: thal, alm, iti, fsi
        if (j < 1280)      v =  fmaxf(thal2fsi[il * HIDN + (j - 1024)], 0.f);
        else if (j < 1536) v =  fmaxf(alm2fsi[il * HIDN + (j - 1280)], 0.f);
        else if (j < 1600) v =  fmaxf(iti2fsi[il * INPN + (j - 1536)], 0.f);
        else               v = -fmaxf(fsi2fsi[il * FSIN + (j - 1600)], 0.f);
        break;
      }
    }
    ws[idx] = v;
  } else if (idx < WTOTAL + BATCH * TOT) {
    int q = idx - WTOTAL;
    ws[HA_OFF + q] = hn[q];
  } else if (idx < WTOTAL + 2 * BATCH * TOT) {
    int q = idx - WTOTAL - BATCH * TOT;
    ws[X_OFF + q] = xn[q];
  }
}

__global__ __launch_bounds__(256)
void step_kernel(const float* __restrict__ inp,   const float* __restrict__ cue,
                 const float* __restrict__ inhib, const float* __restrict__ noise,
                 float* __restrict__ ws, float* __restrict__ out, int t)
{
  const int slot = blockIdx.x % 7;
  const int b    = blockIdx.x / 7;
  const int tid  = threadIdx.x;
  const int wv   = tid >> 6;
  const int lane = tid & 63;

  __shared__ float h_sh[TOT];
  __shared__ float pacc[4][256];

  float* __restrict__ h_src = ws + ((t & 1) ? HB_OFF : HA_OFF);
  float* __restrict__ h_dst = ws + ((t & 1) ? HA_OFF : HB_OFF);
  float* __restrict__ x_st  = ws + X_OFF;

  // ---- epilogue prefetch (hide HBM latency of inhib/noise behind the dot)
  int ep_i = -1;
  float inh_v = 0.f, noi_v = 0.f, xold = 0.f;
  if (slot < 6) ep_i = g_ibase[slot] + tid;
  else if (tid < 140) ep_i = 1536 + tid;  // 64 iti + 76 fsi
  if (ep_i >= 0) {
    size_t o = (size_t)(b * NSTEP + t) * TOT + ep_i;
    inh_v = inhib[o];
    noi_v = noise[o];
    xold  = x_st[b * TOT + ep_i];
  }
  const float inp_t = inp[b * NSTEP + t];
  const float cue_t = cue[b * NSTEP + t];

  // ---- stage h[b] into LDS
  for (int q = tid; q < TOT; q += 256) h_sh[q] = h_src[b * TOT + q];
  __syncthreads();

  // ---- dot products: 4 waves split K, each lane owns 4 output cols (float4)
  const int K  = g_K[slot];
  const int ip = g_ip[slot];
  const int il4 = lane * 4;
  const int Kq = (K + 3) >> 2;
  const int k0 = wv * Kq;
  const int k1 = min(K, k0 + Kq);

  if (il4 < ip) {
    float a0 = 0.f, a1 = 0.f, a2 = 0.f, a3 = 0.f;
    const float* __restrict__ wbase = ws + g_woff[slot];
    int koff = 0;
    for (int s = 0; s < g_nseg[slot]; ++s) {
      const int len = g_seglen[slot][s];
      const int lo = max(k0 - koff, 0);
      const int hi = min(k1 - koff, len);
      if (lo < hi) {
        const float* __restrict__ wp = wbase + (size_t)(koff + lo) * ip + il4;
        const float* __restrict__ hp = h_sh + g_segstart[slot][s] + lo;
        const int n = hi - lo;
        #pragma unroll 8
        for (int q = 0; q < n; ++q) {
          float hj = hp[q];
          float4 w = *(const float4*)wp;
          a0 = fmaf(w.x, hj, a0);
          a1 = fmaf(w.y, hj, a1);
          a2 = fmaf(w.z, hj, a2);
          a3 = fmaf(w.w, hj, a3);
          wp += ip;
        }
      }
      koff += len;
    }
    *(float4*)&pacc[wv][il4] = make_float4(a0, a1, a2, a3);
  }
  __syncthreads();

  // ---- reduce partials + Euler update + relu + store
  if (ep_i >= 0) {
    float drive;
    if (slot < 6) {
      drive = pacc[0][tid] + pacc[1][tid] + pacc[2][tid] + pacc[3][tid];
      drive += g_tonic[slot];
      if (slot == 4) drive += cue_t;       // thal gets cue input
    } else if (tid < 64) {
      drive = inp_t;                        // iti rows: zero W row, inp mask
    } else {
      int il = tid - 64;
      drive = pacc[0][il] + pacc[1][il] + pacc[2][il] + pacc[3][il];
    }
    drive += inh_v + SCALE * noi_v;
    float x = xold + DT * (drive - xold);
    float h = fmaxf(x, 0.f);
    x_st[b * TOT + ep_i]  = x;
    h_dst[b * TOT + ep_i] = h;
    out[(size_t)(b * NSTEP + t) * TOT + ep_i] = h;
  }
}

extern "C" void kernel_launch(void* const* d_in, const int* in_sizes, int n_in,
                              void* d_out, int out_size, void* d_ws, size_t ws_size,
                              hipStream_t stream) {
  const float* inp   = (const float*)d_in[0];
  const float* cue   = (const float*)d_in[1];
  const float* hn    = (const float*)d_in[2];
  const float* xn    = (const float*)d_in[3];
  const float* inhib = (const float*)d_in[4];
  const float* noise = (const float*)d_in[5];
  float* ws  = (float*)d_ws;
  float* out = (float*)d_out;

  build_kernel<<<(881920 + 255) / 256, 256, 0, stream>>>(
      (const float*)d_in[6],  (const float*)d_in[7],  (const float*)d_in[8],
      (const float*)d_in[9],  (const float*)d_in[10], (const float*)d_in[11],
      (const float*)d_in[12], (const float*)d_in[13], (const float*)d_in[14],
      (const float*)d_in[15], (const float*)d_in[16], (const float*)d_in[17],
      (const float*)d_in[18], (const float*)d_in[19], (const float*)d_in[20],
      (const float*)d_in[21], (const float*)d_in[22], (const float*)d_in[23],
      hn, xn, ws);

  for (int t = 0; t < NSTEP; ++t) {
    step_kernel<<<BATCH * 7, 256, 0, stream>>>(inp, cue, inhib, noise, ws, out, t);
  }
}